// Round 5
// baseline (634.149 us; speedup 1.0000x reference)
//
#include <hip/hip_runtime.h>
#include <hip/hip_bf16.h>

// Shapes (fixed): B=128, F=8, K=256, D=256, H=256, HFF=512, L=2, M_PREV=2
#define B_   128
#define F_   8
#define K_   256
#define D_   256
#define H_   256
#define HFF_ 512
#define RT   64   // candidates per block

typedef _Float16 half8  __attribute__((ext_vector_type(8)));  // f16x8 MFMA frag
typedef _Float16 half4v __attribute__((ext_vector_type(4)));
typedef float floatx4   __attribute__((ext_vector_type(4)));  // MFMA acc

#define MFMAH(a,b,c) __builtin_amdgcn_mfma_f32_16x16x32_f16(a,b,c,0,0,0)

// R14 (= R13 with the k_resfin missing-`x`-param compile fix):
// k_main is the verified R9 config (365us, 3 blk/CU) — R10/R12 ablations
// proved occupancy/LDS/barrier perturbations all hurt.
// k_resfin merges k_rescore+k_final (8 candidates/block, weights read
// once per 8, float4 LDS broadcasts, winner cw kept in LDS -> no recompute).
#define HA_S  260
#define HMA_S 132

// ---------------------------------------------------------------------------
// R9: fused prep — one launch for (h0->u), v, and the fp16 weight shuffle.
__global__ void k_prep(const float* __restrict__ cb, const float* __restrict__ Win,
                       const float* __restrict__ bin, const float* __restrict__ Wcat,
                       const float* __restrict__ bcat, const float* __restrict__ xhat,
                       const float* __restrict__ W1, const float* __restrict__ W2,
                       const float* __restrict__ Wout,
                       float* __restrict__ u, float* __restrict__ v,
                       _Float16* __restrict__ w1f, _Float16* __restrict__ w2f,
                       _Float16* __restrict__ wof) {
  const int blk = blockIdx.x, t = threadIdx.x;
  if (blk < K_) {
    __shared__ float row[D_];
    __shared__ float h0row[H_];
    row[t] = cb[blk * D_ + t];
    __syncthreads();
    float acc = bin[t];
    #pragma unroll 4
    for (int i = 0; i < D_; ++i) acc = fmaf(row[i], Win[i * H_ + t], acc);
    h0row[t] = acc;
    __syncthreads();
    float acc2 = 0.f;
    #pragma unroll 4
    for (int i = 0; i < H_; ++i) acc2 = fmaf(h0row[i], Wcat[i * H_ + t], acc2);
    u[blk * H_ + t] = acc2;
  } else if (blk < K_ + B_ * F_) {
    __shared__ float row2[D_];
    const int bf = blk - K_;
    row2[t] = xhat[bf * D_ + t];
    __syncthreads();
    float acc = bcat[t];
    #pragma unroll 4
    for (int i = 0; i < D_; ++i) acc = fmaf(row2[i], Wcat[(H_ + i) * H_ + t], acc);
    v[bf * H_ + t] = acc;
  } else {
    const int e = (blk - (K_ + B_ * F_)) * 256 + t;
    const float* src; _Float16* dst; int N, NT, le;
    if (e < 262144) {
      const int layer = e >> 17; le = e & 131071;
      src = W1 + layer * (H_ * HFF_); dst = w1f + layer * (H_ * HFF_);
      N = HFF_; NT = 32;
    } else if (e < 524288) {
      const int e2 = e - 262144;
      const int layer = e2 >> 17; le = e2 & 131071;
      src = W2 + layer * (HFF_ * H_); dst = w2f + layer * (HFF_ * H_);
      N = H_; NT = 16;
    } else {
      le = e - 524288; src = Wout; dst = wof; N = D_; NT = 16;
    }
    const int jj = le & 7, lane = (le >> 3) & 63, r = le >> 9;
    const int ntile = r % NT, kstep = r / NT;
    const int row = kstep * 32 + (lane >> 4) * 8 + jj;
    const int colc = ntile * 16 + (lane & 15);
    dst[le] = (_Float16)src[row * N + colc];
  }
}

// ---------------------------------------------------------------------------
// MFMA main kernel (R9 verified config): C' = W^T @ h^T, fp16, 64 cand/block.
__global__ __launch_bounds__(256, 3) void k_main(
    const float* __restrict__ u, const float* __restrict__ v,
    const _Float16* __restrict__ w1f, const float* __restrict__ b1,
    const _Float16* __restrict__ w2f, const float* __restrict__ b2,
    const _Float16* __restrict__ woutf, const float* __restrict__ bout,
    const float* __restrict__ cb, const float* __restrict__ xhat,
    const float* __restrict__ x, float* __restrict__ dists) {
  __shared__ _Float16 hA[64][HA_S];    // 33280 B
  __shared__ _Float16 hmA[64][HMA_S];  // 16896 B
  __shared__ float x_s[D_], xh_s[D_];  // 2048 B
  __shared__ float dist_s[4][64];      // 1024 B

  const int t = threadIdx.x;
  const int blk = blockIdx.x;
  const int bf = blk >> 2, k0 = (blk & 3) << 6;
  const int b = bf >> 3, f = bf & 7;
  const int wave = t >> 6, lane = t & 63;
  const int col = lane & 15, quad = lane >> 4;
  const int lane8 = lane * 8;

  x_s[t]  = x[b * D_ + t];
  xh_s[t] = xhat[bf * D_ + t];

  // stage h = u + v -> fp16, packed 16B writes
  {
    const int r = t >> 2, c0 = (t & 3) * 64;
    const float* up = u + (k0 + r) * H_ + c0;
    const float* vp = v + bf * H_ + c0;
    #pragma unroll
    for (int j = 0; j < 64; j += 8) {
      float4 uA = *(const float4*)(up + j);
      float4 vA = *(const float4*)(vp + j);
      float4 uB = *(const float4*)(up + j + 4);
      float4 vB = *(const float4*)(vp + j + 4);
      half8 hv8;
      hv8[0] = (_Float16)(uA.x + vA.x); hv8[1] = (_Float16)(uA.y + vA.y);
      hv8[2] = (_Float16)(uA.z + vA.z); hv8[3] = (_Float16)(uA.w + vA.w);
      hv8[4] = (_Float16)(uB.x + vB.x); hv8[5] = (_Float16)(uB.y + vB.y);
      hv8[6] = (_Float16)(uB.z + vB.z); hv8[7] = (_Float16)(uB.w + vB.w);
      *(half8*)&hA[r][c0 + j] = hv8;
    }
  }
  __syncthreads();

  const floatx4 zero4 = {0.f, 0.f, 0.f, 0.f};

  #pragma unroll 1
  for (int l = 0; l < 2; ++l) {
    const _Float16* w1_l = w1f + l * (H_ * HFF_);
    const _Float16* w2_l = w2f + l * (HFF_ * H_);
    const float* b1l = b1 + l * HFF_;
    const float* b2l = b2 + l * H_;

    floatx4 acc2[4][4];   // [out-feature tile][candidate-row tile]
    #pragma unroll
    for (int mt = 0; mt < 4; ++mt)
      #pragma unroll
      for (int nt = 0; nt < 4; ++nt) acc2[mt][nt] = zero4;

    #pragma unroll 1
    for (int ch = 0; ch < 4; ++ch) {
      // ---- GEMM1': hm' = relu(W1[:,chunk]^T @ h^T + b1) ----
      floatx4 acc1[2][4];
      #pragma unroll
      for (int mt = 0; mt < 2; ++mt)
        #pragma unroll
        for (int nt = 0; nt < 4; ++nt) acc1[mt][nt] = zero4;

      const _Float16* w1_b = w1_l + (ch * 8 + wave * 2) * 512 + lane8;

      #pragma unroll 4
      for (int ks = 0; ks < 8; ++ks) {
        half8 b0 = *(const half8*)&hA[col][ks * 32 + quad * 8];
        half8 b1v = *(const half8*)&hA[16 + col][ks * 32 + quad * 8];
        half8 b2v = *(const half8*)&hA[32 + col][ks * 32 + quad * 8];
        half8 b3v = *(const half8*)&hA[48 + col][ks * 32 + quad * 8];
        const int ko = ks * 32 * 512;
        #pragma unroll
        for (int mt = 0; mt < 2; ++mt) {
          half8 aw = *(const half8*)(w1_b + ko + mt * 512);
          acc1[mt][0] = MFMAH(aw, b0, acc1[mt][0]);
          acc1[mt][1] = MFMAH(aw, b1v, acc1[mt][1]);
          acc1[mt][2] = MFMAH(aw, b2v, acc1[mt][2]);
          acc1[mt][3] = MFMAH(aw, b3v, acc1[mt][3]);
        }
      }
      // bias + relu -> fp16, packed 8B stores (4 consecutive features/lane)
      #pragma unroll
      for (int mt = 0; mt < 2; ++mt) {
        const int floc = (wave * 2 + mt) * 16 + quad * 4;
        float4 bb = *(const float4*)&b1l[ch * 128 + floc];
        #pragma unroll
        for (int nt = 0; nt < 4; ++nt) {
          const int row = nt * 16 + col;
          half4v nh;
          #pragma unroll
          for (int p = 0; p < 4; ++p)
            nh[p] = (_Float16)fmaxf(acc1[mt][nt][p] + ((const float*)&bb)[p], 0.f);
          *(half4v*)&hmA[row][floc] = nh;
        }
      }
      __syncthreads();

      // ---- GEMM2': acc2 += W2[chunk,:]^T @ hm'^T ----
      const _Float16* w2_b = w2_l + (ch * 64 + wave * 4) * 512 + lane8;
      #pragma unroll 2
      for (int ks = 0; ks < 4; ++ks) {
        half8 b0 = *(const half8*)&hmA[col][ks * 32 + quad * 8];
        half8 b1v = *(const half8*)&hmA[16 + col][ks * 32 + quad * 8];
        half8 b2v = *(const half8*)&hmA[32 + col][ks * 32 + quad * 8];
        half8 b3v = *(const half8*)&hmA[48 + col][ks * 32 + quad * 8];
        const int ko = ks * 16 * 512;
        #pragma unroll
        for (int mt = 0; mt < 4; ++mt) {
          half8 aw = *(const half8*)(w2_b + ko + mt * 512);
          acc2[mt][0] = MFMAH(aw, b0, acc2[mt][0]);
          acc2[mt][1] = MFMAH(aw, b1v, acc2[mt][1]);
          acc2[mt][2] = MFMAH(aw, b2v, acc2[mt][2]);
          acc2[mt][3] = MFMAH(aw, b3v, acc2[mt][3]);
        }
      }
      __syncthreads();
    }

    // ---- residual: h += acc2 + b2, packed 8B read/modify/write ----
    #pragma unroll
    for (int mt = 0; mt < 4; ++mt) {
      const int feat0 = (wave * 4 + mt) * 16 + quad * 4;
      float4 bb = *(const float4*)&b2l[feat0];
      #pragma unroll
      for (int nt = 0; nt < 4; ++nt) {
        const int row = nt * 16 + col;
        half4v oh = *(half4v*)&hA[row][feat0];
        half4v nh;
        #pragma unroll
        for (int p = 0; p < 4; ++p)
          nh[p] = (_Float16)((float)oh[p] + acc2[mt][nt][p] + ((const float*)&bb)[p]);
        *(half4v*)&hA[row][feat0] = nh;
      }
    }
    __syncthreads();
  }

  // ---- GEMM3': cw' = Wout^T @ h^T (+bout+cb+xhat), then distance ----
  floatx4 acc3[4][4];
  #pragma unroll
  for (int mt = 0; mt < 4; ++mt)
    #pragma unroll
    for (int nt = 0; nt < 4; ++nt) acc3[mt][nt] = zero4;

  const _Float16* wo_b = woutf + (wave * 4) * 512 + lane8;
  #pragma unroll 2
  for (int ks = 0; ks < 8; ++ks) {
    half8 b0 = *(const half8*)&hA[col][ks * 32 + quad * 8];
    half8 b1v = *(const half8*)&hA[16 + col][ks * 32 + quad * 8];
    half8 b2v = *(const half8*)&hA[32 + col][ks * 32 + quad * 8];
    half8 b3v = *(const half8*)&hA[48 + col][ks * 32 + quad * 8];
    const int ko = ks * 16 * 512;
    #pragma unroll
    for (int mt = 0; mt < 4; ++mt) {
      half8 aw = *(const half8*)(wo_b + ko + mt * 512);
      acc3[mt][0] = MFMAH(aw, b0, acc3[mt][0]);
      acc3[mt][1] = MFMAH(aw, b1v, acc3[mt][1]);
      acc3[mt][2] = MFMAH(aw, b2v, acc3[mt][2]);
      acc3[mt][3] = MFMAH(aw, b3v, acc3[mt][3]);
    }
  }

  float s[4] = {0.f, 0.f, 0.f, 0.f};
  #pragma unroll
  for (int mt = 0; mt < 4; ++mt) {
    const int d0 = (wave * 4 + mt) * 16 + quad * 4;
    float4 bo = *(const float4*)&bout[d0];
    float4 xv = *(const float4*)&x_s[d0];
    float4 xh4 = *(const float4*)&xh_s[d0];
    #pragma unroll
    for (int nt = 0; nt < 4; ++nt) {
      float4 cbv = *(const float4*)&cb[(k0 + nt * 16 + col) * D_ + d0];
      #pragma unroll
      for (int p = 0; p < 4; ++p) {
        float base = ((const float*)&bo)[p] + ((const float*)&xh4)[p];
        float xx = ((const float*)&xv)[p];
        float cw = acc3[mt][nt][p] + base + ((const float*)&cbv)[p];
        s[nt] += cw * (cw - 2.f * xx);   // -||x||^2 const: argmin-invariant
      }
    }
  }
  #pragma unroll
  for (int nt = 0; nt < 4; ++nt) {
    s[nt] += __shfl_xor(s[nt], 16, 64);
    s[nt] += __shfl_xor(s[nt], 32, 64);
  }
  if (quad == 0) {
    #pragma unroll
    for (int nt = 0; nt < 4; ++nt)
      dist_s[wave][nt * 16 + col] = s[nt];
  }
  __syncthreads();
  if (t < 64) {
    float d = dist_s[0][t] + dist_s[1][t] + dist_s[2][t] + dist_s[3][t];
    dists[b * (F_ * K_) + f * K_ + k0 + t] = d;
  }
}

// ---------------------------------------------------------------------------
// Top-8 candidates per b from approx dists (iterative selection).
__global__ void k_top8(const float* __restrict__ dists, int* __restrict__ topi) {
  __shared__ float ds[F_ * K_];
  __shared__ float bv[256];
  __shared__ int bi_s[256];
  const int b = blockIdx.x, t = threadIdx.x;
  for (int j = t; j < F_ * K_; j += 256) ds[j] = dists[b * (F_ * K_) + j];
  __syncthreads();
  for (int pass = 0; pass < 8; ++pass) {
    float best = 3.4e38f; int bi = 0;
    for (int j = t; j < F_ * K_; j += 256) {
      const float dv = ds[j];
      if (dv < best) { best = dv; bi = j; }
    }
    bv[t] = best; bi_s[t] = bi;
    __syncthreads();
    for (int s = 128; s > 0; s >>= 1) {
      if (t < s) {
        const float ov = bv[t + s]; const int oi = bi_s[t + s];
        if (ov < bv[t] || (ov == bv[t] && oi < bi_s[t])) { bv[t] = ov; bi_s[t] = oi; }
      }
      __syncthreads();
    }
    if (t == 0) { topi[b * 8 + pass] = bi_s[0]; ds[bi_s[0]] = 3.4e38f; }
    __syncthreads();
  }
}

// ---------------------------------------------------------------------------
// R14: merged exact rescore + final. One block per b; all 8 candidates
// batched so weights are read ONCE per block (8x less L2 traffic than the
// old k_rescore) and k_final's full weight pass + serial recompute is gone
// (winner cw vector is kept in LDS). Per-candidate fma chain order is
// IDENTICAL to the old k_rescore (sequential i / jj), so numerics match.
#define NC 8
__global__ __launch_bounds__(256) void k_resfin(
    const float* __restrict__ u, const float* __restrict__ v,
    const float* __restrict__ W1, const float* __restrict__ b1,
    const float* __restrict__ W2, const float* __restrict__ b2,
    const float* __restrict__ Wout, const float* __restrict__ bout,
    const float* __restrict__ cb, const float* __restrict__ xhat,
    const float* __restrict__ x, const int* __restrict__ codes,
    const int* __restrict__ topi, float* __restrict__ out) {
  __shared__ float hs8[NC][H_ + 4];     // 8320 B  (rows 16B-aligned: 260*4)
  __shared__ float hms8[NC][HFF_ + 4];  // 16512 B (516*4)
  __shared__ float cw8[NC][H_ + 4];     // 8320 B
  __shared__ float redw[4][NC];
  __shared__ int   idx_sh;

  const int b = blockIdx.x, t = threadIdx.x;
  const int wave = t >> 6, lane = t & 63;

  int kc[NC], bfc[NC], ixc[NC];
  #pragma unroll
  for (int c = 0; c < NC; ++c) {
    const int ix = topi[b * 8 + c];
    ixc[c] = ix;
    kc[c] = ix & 255;
    bfc[c] = b * F_ + (ix >> 8);
  }

  // hs init: hs[c][t] = u[k_c][t] + v[bf_c][t]  (coalesced per c)
  #pragma unroll
  for (int c = 0; c < NC; ++c)
    hs8[c][t] = u[kc[c] * H_ + t] + v[bfc[c] * H_ + t];
  __syncthreads();

  #pragma unroll 1
  for (int l = 0; l < 2; ++l) {
    const float* W1l = W1 + l * (H_ * HFF_);
    const float* W2l = W2 + l * (HFF_ * H_);

    // ---- hm = relu(h @ W1 + b1): thread t owns outputs t and t+256 ----
    float a0[NC], a1[NC];
    {
      const float bb0 = b1[l * HFF_ + t], bb1 = b1[l * HFF_ + 256 + t];
      #pragma unroll
      for (int c = 0; c < NC; ++c) { a0[c] = bb0; a1[c] = bb1; }
    }
    #pragma unroll 2
    for (int i = 0; i < H_; i += 4) {
      float4 hv[NC];
      #pragma unroll
      for (int c = 0; c < NC; ++c) hv[c] = *(const float4*)&hs8[c][i];
      #pragma unroll
      for (int q = 0; q < 4; ++q) {
        const float w0 = W1l[(i + q) * HFF_ + t];
        const float w1 = W1l[(i + q) * HFF_ + 256 + t];
        #pragma unroll
        for (int c = 0; c < NC; ++c) {
          const float h = ((const float*)&hv[c])[q];
          a0[c] = fmaf(h, w0, a0[c]);
          a1[c] = fmaf(h, w1, a1[c]);
        }
      }
    }
    #pragma unroll
    for (int c = 0; c < NC; ++c) {
      hms8[c][t] = fmaxf(a0[c], 0.f);
      hms8[c][t + 256] = fmaxf(a1[c], 0.f);
    }
    __syncthreads();

    // ---- h = h + hm @ W2 + b2 ----
    float hn[NC];
    {
      const float bb2 = b2[l * H_ + t];
      #pragma unroll
      for (int c = 0; c < NC; ++c) hn[c] = hs8[c][t] + bb2;
    }
    #pragma unroll 2
    for (int jj = 0; jj < HFF_; jj += 4) {
      float4 hv[NC];
      #pragma unroll
      for (int c = 0; c < NC; ++c) hv[c] = *(const float4*)&hms8[c][jj];
      #pragma unroll
      for (int q = 0; q < 4; ++q) {
        const float w = W2l[(jj + q) * H_ + t];
        #pragma unroll
        for (int c = 0; c < NC; ++c)
          hn[c] = fmaf(((const float*)&hv[c])[q], w, hn[c]);
      }
    }
    __syncthreads();   // all reads of hs8/hms8 done before overwrite
    #pragma unroll
    for (int c = 0; c < NC; ++c) hs8[c][t] = hn[c];
    __syncthreads();
  }

  // ---- cw = h @ Wout + bout + cb + xhat; distance partials ----
  float cw[NC];
  {
    const float bo = bout[t];
    #pragma unroll
    for (int c = 0; c < NC; ++c)
      cw[c] = bo + cb[kc[c] * D_ + t] + xhat[bfc[c] * D_ + t];
  }
  #pragma unroll 2
  for (int i = 0; i < H_; i += 4) {
    float4 hv[NC];
    #pragma unroll
    for (int c = 0; c < NC; ++c) hv[c] = *(const float4*)&hs8[c][i];
    #pragma unroll
    for (int q = 0; q < 4; ++q) {
      const float w = Wout[(i + q) * D_ + t];
      #pragma unroll
      for (int c = 0; c < NC; ++c)
        cw[c] = fmaf(((const float*)&hv[c])[q], w, cw[c]);
    }
  }

  const float xx = x[b * D_ + t];
  float p[NC];
  #pragma unroll
  for (int c = 0; c < NC; ++c) {
    cw8[c][t] = cw[c];
    p[c] = cw[c] * (cw[c] - 2.f * xx);
  }
  // wave reduce (full 64-lane sum), then cross-wave via LDS
  #pragma unroll
  for (int c = 0; c < NC; ++c) {
    float vsum = p[c];
    vsum += __shfl_xor(vsum, 1, 64);
    vsum += __shfl_xor(vsum, 2, 64);
    vsum += __shfl_xor(vsum, 4, 64);
    vsum += __shfl_xor(vsum, 8, 64);
    vsum += __shfl_xor(vsum, 16, 64);
    vsum += __shfl_xor(vsum, 32, 64);
    if (lane == 0) redw[wave][c] = vsum;
  }
  __syncthreads();
  if (t == 0) {
    float bd = 3.4e38f; int bidx = 1 << 30; int bc = 0;
    #pragma unroll
    for (int c = 0; c < NC; ++c) {
      const float d = redw[0][c] + redw[1][c] + redw[2][c] + redw[3][c];
      if (d < bd || (d == bd && ixc[c] < bidx)) { bd = d; bidx = ixc[c]; bc = c; }
    }
    idx_sh = bc;
  }
  __syncthreads();
  const int cwin = idx_sh;

  out[b * D_ + t] = cw8[cwin][t];
  if (t < 2)
    out[B_ * D_ + t * B_ + b] = (float)codes[t * B_ + b];
  else if (t == 2)
    out[B_ * D_ + 2 * B_ + b] = (float)ixc[cwin];
}

// ---------------------------------------------------------------------------
extern "C" void kernel_launch(void* const* d_in, const int* in_sizes, int n_in,
                              void* d_out, int out_size, void* d_ws, size_t ws_size,
                              hipStream_t stream) {
  const float* x    = (const float*)d_in[0];
  const float* xhat = (const float*)d_in[1];
  const int*   codes= (const int*)d_in[2];
  const float* cb   = (const float*)d_in[3];
  const float* Win  = (const float*)d_in[4];
  const float* bin  = (const float*)d_in[5];
  const float* Wcat = (const float*)d_in[6];
  const float* bcat = (const float*)d_in[7];
  const float* W1   = (const float*)d_in[8];
  const float* b1   = (const float*)d_in[9];
  const float* W2   = (const float*)d_in[10];
  const float* b2   = (const float*)d_in[11];
  const float* Wout = (const float*)d_in[12];
  const float* bout = (const float*)d_in[13];
  float* out = (float*)d_out;

  float* u     = (float*)d_ws;                  // 65536 f (h0 eliminated)
  float* v     = u + K_ * H_;                   // 262144 f
  float* dists = v + B_ * F_ * H_;              // 262144 f
  float* resc  = dists + B_ * F_ * K_;          // 1024 f (unused, kept for layout)
  int*   topi  = (int*)(resc + 1024);           // 1024 i
  int*   pad   = topi + 1024;                   // 128 pad (keeps 16B align)
  _Float16* w1f  = (_Float16*)(pad + 128);      // 2*H*HFF halves
  _Float16* w2f  = w1f + 2 * H_ * HFF_;
  _Float16* wof  = w2f + 2 * HFF_ * H_;

  k_prep<<<K_ + B_ * F_ + 2304, 256, 0, stream>>>(cb, Win, bin, Wcat, bcat, xhat,
                                                  W1, W2, Wout, u, v, w1f, w2f, wof);

  k_main<<<B_ * F_ * (K_ / RT), 256, 0, stream>>>(u, v, w1f, b1, w2f, b2,
                                                  wof, bout, cb, xhat, x, dists);
  k_top8<<<B_, 256, 0, stream>>>(dists, topi);
  k_resfin<<<B_, 256, 0, stream>>>(u, v, W1, b1, W2, b2, Wout, bout, cb, xhat,
                                   x, codes, topi, out);
}

// Round 6
// 541.112 us; speedup vs baseline: 1.1719x; 1.1719x over previous
//
#include <hip/hip_runtime.h>
#include <hip/hip_bf16.h>

// Shapes (fixed): B=128, F=8, K=256, D=256, H=256, HFF=512, L=2, M_PREV=2
#define B_   128
#define F_   8
#define K_   256
#define D_   256
#define H_   256
#define HFF_ 512
#define RT   64   // candidates per block

typedef _Float16 half8  __attribute__((ext_vector_type(8)));  // f16x8 MFMA frag
typedef _Float16 half4v __attribute__((ext_vector_type(4)));
typedef float floatx4   __attribute__((ext_vector_type(4)));  // MFMA acc

#define MFMAH(a,b,c) __builtin_amdgcn_mfma_f32_16x16x32_f16(a,b,c,0,0,0)

// R15: k_main = verified R9 config (365us). Side-kernel fix v2:
// R14's k_resfin (128 blocks, 1 wave/SIMD) was latency-bound (~215us, ~7%
// issue efficiency). Split to 256 blocks x 512 thr: block (b,half) owns 4
// candidates, two 256-thread groups of 2 candidates each -> all 256 CUs
// active, 2 waves/SIMD, 4x less work/thread. Cross-half argmin -> tiny
// k_finw (compare 2 pairs + copy stored winner row; no weight pass).
#define HA_S  260
#define HMA_S 132

// ---------------------------------------------------------------------------
// R9: fused prep — one launch for (h0->u), v, and the fp16 weight shuffle.
__global__ void k_prep(const float* __restrict__ cb, const float* __restrict__ Win,
                       const float* __restrict__ bin, const float* __restrict__ Wcat,
                       const float* __restrict__ bcat, const float* __restrict__ xhat,
                       const float* __restrict__ W1, const float* __restrict__ W2,
                       const float* __restrict__ Wout,
                       float* __restrict__ u, float* __restrict__ v,
                       _Float16* __restrict__ w1f, _Float16* __restrict__ w2f,
                       _Float16* __restrict__ wof) {
  const int blk = blockIdx.x, t = threadIdx.x;
  if (blk < K_) {
    __shared__ float row[D_];
    __shared__ float h0row[H_];
    row[t] = cb[blk * D_ + t];
    __syncthreads();
    float acc = bin[t];
    #pragma unroll 4
    for (int i = 0; i < D_; ++i) acc = fmaf(row[i], Win[i * H_ + t], acc);
    h0row[t] = acc;
    __syncthreads();
    float acc2 = 0.f;
    #pragma unroll 4
    for (int i = 0; i < H_; ++i) acc2 = fmaf(h0row[i], Wcat[i * H_ + t], acc2);
    u[blk * H_ + t] = acc2;
  } else if (blk < K_ + B_ * F_) {
    __shared__ float row2[D_];
    const int bf = blk - K_;
    row2[t] = xhat[bf * D_ + t];
    __syncthreads();
    float acc = bcat[t];
    #pragma unroll 4
    for (int i = 0; i < D_; ++i) acc = fmaf(row2[i], Wcat[(H_ + i) * H_ + t], acc);
    v[bf * H_ + t] = acc;
  } else {
    const int e = (blk - (K_ + B_ * F_)) * 256 + t;
    const float* src; _Float16* dst; int N, NT, le;
    if (e < 262144) {
      const int layer = e >> 17; le = e & 131071;
      src = W1 + layer * (H_ * HFF_); dst = w1f + layer * (H_ * HFF_);
      N = HFF_; NT = 32;
    } else if (e < 524288) {
      const int e2 = e - 262144;
      const int layer = e2 >> 17; le = e2 & 131071;
      src = W2 + layer * (HFF_ * H_); dst = w2f + layer * (HFF_ * H_);
      N = H_; NT = 16;
    } else {
      le = e - 524288; src = Wout; dst = wof; N = D_; NT = 16;
    }
    const int jj = le & 7, lane = (le >> 3) & 63, r = le >> 9;
    const int ntile = r % NT, kstep = r / NT;
    const int row = kstep * 32 + (lane >> 4) * 8 + jj;
    const int colc = ntile * 16 + (lane & 15);
    dst[le] = (_Float16)src[row * N + colc];
  }
}

// ---------------------------------------------------------------------------
// MFMA main kernel (R9 verified config): C' = W^T @ h^T, fp16, 64 cand/block.
__global__ __launch_bounds__(256, 3) void k_main(
    const float* __restrict__ u, const float* __restrict__ v,
    const _Float16* __restrict__ w1f, const float* __restrict__ b1,
    const _Float16* __restrict__ w2f, const float* __restrict__ b2,
    const _Float16* __restrict__ woutf, const float* __restrict__ bout,
    const float* __restrict__ cb, const float* __restrict__ xhat,
    const float* __restrict__ x, float* __restrict__ dists) {
  __shared__ _Float16 hA[64][HA_S];    // 33280 B
  __shared__ _Float16 hmA[64][HMA_S];  // 16896 B
  __shared__ float x_s[D_], xh_s[D_];  // 2048 B
  __shared__ float dist_s[4][64];      // 1024 B

  const int t = threadIdx.x;
  const int blk = blockIdx.x;
  const int bf = blk >> 2, k0 = (blk & 3) << 6;
  const int b = bf >> 3, f = bf & 7;
  const int wave = t >> 6, lane = t & 63;
  const int col = lane & 15, quad = lane >> 4;
  const int lane8 = lane * 8;

  x_s[t]  = x[b * D_ + t];
  xh_s[t] = xhat[bf * D_ + t];

  // stage h = u + v -> fp16, packed 16B writes
  {
    const int r = t >> 2, c0 = (t & 3) * 64;
    const float* up = u + (k0 + r) * H_ + c0;
    const float* vp = v + bf * H_ + c0;
    #pragma unroll
    for (int j = 0; j < 64; j += 8) {
      float4 uA = *(const float4*)(up + j);
      float4 vA = *(const float4*)(vp + j);
      float4 uB = *(const float4*)(up + j + 4);
      float4 vB = *(const float4*)(vp + j + 4);
      half8 hv8;
      hv8[0] = (_Float16)(uA.x + vA.x); hv8[1] = (_Float16)(uA.y + vA.y);
      hv8[2] = (_Float16)(uA.z + vA.z); hv8[3] = (_Float16)(uA.w + vA.w);
      hv8[4] = (_Float16)(uB.x + vB.x); hv8[5] = (_Float16)(uB.y + vB.y);
      hv8[6] = (_Float16)(uB.z + vB.z); hv8[7] = (_Float16)(uB.w + vB.w);
      *(half8*)&hA[r][c0 + j] = hv8;
    }
  }
  __syncthreads();

  const floatx4 zero4 = {0.f, 0.f, 0.f, 0.f};

  #pragma unroll 1
  for (int l = 0; l < 2; ++l) {
    const _Float16* w1_l = w1f + l * (H_ * HFF_);
    const _Float16* w2_l = w2f + l * (HFF_ * H_);
    const float* b1l = b1 + l * HFF_;
    const float* b2l = b2 + l * H_;

    floatx4 acc2[4][4];   // [out-feature tile][candidate-row tile]
    #pragma unroll
    for (int mt = 0; mt < 4; ++mt)
      #pragma unroll
      for (int nt = 0; nt < 4; ++nt) acc2[mt][nt] = zero4;

    #pragma unroll 1
    for (int ch = 0; ch < 4; ++ch) {
      // ---- GEMM1': hm' = relu(W1[:,chunk]^T @ h^T + b1) ----
      floatx4 acc1[2][4];
      #pragma unroll
      for (int mt = 0; mt < 2; ++mt)
        #pragma unroll
        for (int nt = 0; nt < 4; ++nt) acc1[mt][nt] = zero4;

      const _Float16* w1_b = w1_l + (ch * 8 + wave * 2) * 512 + lane8;

      #pragma unroll 4
      for (int ks = 0; ks < 8; ++ks) {
        half8 b0 = *(const half8*)&hA[col][ks * 32 + quad * 8];
        half8 b1v = *(const half8*)&hA[16 + col][ks * 32 + quad * 8];
        half8 b2v = *(const half8*)&hA[32 + col][ks * 32 + quad * 8];
        half8 b3v = *(const half8*)&hA[48 + col][ks * 32 + quad * 8];
        const int ko = ks * 32 * 512;
        #pragma unroll
        for (int mt = 0; mt < 2; ++mt) {
          half8 aw = *(const half8*)(w1_b + ko + mt * 512);
          acc1[mt][0] = MFMAH(aw, b0, acc1[mt][0]);
          acc1[mt][1] = MFMAH(aw, b1v, acc1[mt][1]);
          acc1[mt][2] = MFMAH(aw, b2v, acc1[mt][2]);
          acc1[mt][3] = MFMAH(aw, b3v, acc1[mt][3]);
        }
      }
      // bias + relu -> fp16, packed 8B stores (4 consecutive features/lane)
      #pragma unroll
      for (int mt = 0; mt < 2; ++mt) {
        const int floc = (wave * 2 + mt) * 16 + quad * 4;
        float4 bb = *(const float4*)&b1l[ch * 128 + floc];
        #pragma unroll
        for (int nt = 0; nt < 4; ++nt) {
          const int row = nt * 16 + col;
          half4v nh;
          #pragma unroll
          for (int p = 0; p < 4; ++p)
            nh[p] = (_Float16)fmaxf(acc1[mt][nt][p] + ((const float*)&bb)[p], 0.f);
          *(half4v*)&hmA[row][floc] = nh;
        }
      }
      __syncthreads();

      // ---- GEMM2': acc2 += W2[chunk,:]^T @ hm'^T ----
      const _Float16* w2_b = w2_l + (ch * 64 + wave * 4) * 512 + lane8;
      #pragma unroll 2
      for (int ks = 0; ks < 4; ++ks) {
        half8 b0 = *(const half8*)&hmA[col][ks * 32 + quad * 8];
        half8 b1v = *(const half8*)&hmA[16 + col][ks * 32 + quad * 8];
        half8 b2v = *(const half8*)&hmA[32 + col][ks * 32 + quad * 8];
        half8 b3v = *(const half8*)&hmA[48 + col][ks * 32 + quad * 8];
        const int ko = ks * 16 * 512;
        #pragma unroll
        for (int mt = 0; mt < 4; ++mt) {
          half8 aw = *(const half8*)(w2_b + ko + mt * 512);
          acc2[mt][0] = MFMAH(aw, b0, acc2[mt][0]);
          acc2[mt][1] = MFMAH(aw, b1v, acc2[mt][1]);
          acc2[mt][2] = MFMAH(aw, b2v, acc2[mt][2]);
          acc2[mt][3] = MFMAH(aw, b3v, acc2[mt][3]);
        }
      }
      __syncthreads();
    }

    // ---- residual: h += acc2 + b2, packed 8B read/modify/write ----
    #pragma unroll
    for (int mt = 0; mt < 4; ++mt) {
      const int feat0 = (wave * 4 + mt) * 16 + quad * 4;
      float4 bb = *(const float4*)&b2l[feat0];
      #pragma unroll
      for (int nt = 0; nt < 4; ++nt) {
        const int row = nt * 16 + col;
        half4v oh = *(half4v*)&hA[row][feat0];
        half4v nh;
        #pragma unroll
        for (int p = 0; p < 4; ++p)
          nh[p] = (_Float16)((float)oh[p] + acc2[mt][nt][p] + ((const float*)&bb)[p]);
        *(half4v*)&hA[row][feat0] = nh;
      }
    }
    __syncthreads();
  }

  // ---- GEMM3': cw' = Wout^T @ h^T (+bout+cb+xhat), then distance ----
  floatx4 acc3[4][4];
  #pragma unroll
  for (int mt = 0; mt < 4; ++mt)
    #pragma unroll
    for (int nt = 0; nt < 4; ++nt) acc3[mt][nt] = zero4;

  const _Float16* wo_b = woutf + (wave * 4) * 512 + lane8;
  #pragma unroll 2
  for (int ks = 0; ks < 8; ++ks) {
    half8 b0 = *(const half8*)&hA[col][ks * 32 + quad * 8];
    half8 b1v = *(const half8*)&hA[16 + col][ks * 32 + quad * 8];
    half8 b2v = *(const half8*)&hA[32 + col][ks * 32 + quad * 8];
    half8 b3v = *(const half8*)&hA[48 + col][ks * 32 + quad * 8];
    const int ko = ks * 16 * 512;
    #pragma unroll
    for (int mt = 0; mt < 4; ++mt) {
      half8 aw = *(const half8*)(wo_b + ko + mt * 512);
      acc3[mt][0] = MFMAH(aw, b0, acc3[mt][0]);
      acc3[mt][1] = MFMAH(aw, b1v, acc3[mt][1]);
      acc3[mt][2] = MFMAH(aw, b2v, acc3[mt][2]);
      acc3[mt][3] = MFMAH(aw, b3v, acc3[mt][3]);
    }
  }

  float s[4] = {0.f, 0.f, 0.f, 0.f};
  #pragma unroll
  for (int mt = 0; mt < 4; ++mt) {
    const int d0 = (wave * 4 + mt) * 16 + quad * 4;
    float4 bo = *(const float4*)&bout[d0];
    float4 xv = *(const float4*)&x_s[d0];
    float4 xh4 = *(const float4*)&xh_s[d0];
    #pragma unroll
    for (int nt = 0; nt < 4; ++nt) {
      float4 cbv = *(const float4*)&cb[(k0 + nt * 16 + col) * D_ + d0];
      #pragma unroll
      for (int p = 0; p < 4; ++p) {
        float base = ((const float*)&bo)[p] + ((const float*)&xh4)[p];
        float xx = ((const float*)&xv)[p];
        float cw = acc3[mt][nt][p] + base + ((const float*)&cbv)[p];
        s[nt] += cw * (cw - 2.f * xx);   // -||x||^2 const: argmin-invariant
      }
    }
  }
  #pragma unroll
  for (int nt = 0; nt < 4; ++nt) {
    s[nt] += __shfl_xor(s[nt], 16, 64);
    s[nt] += __shfl_xor(s[nt], 32, 64);
  }
  if (quad == 0) {
    #pragma unroll
    for (int nt = 0; nt < 4; ++nt)
      dist_s[wave][nt * 16 + col] = s[nt];
  }
  __syncthreads();
  if (t < 64) {
    float d = dist_s[0][t] + dist_s[1][t] + dist_s[2][t] + dist_s[3][t];
    dists[b * (F_ * K_) + f * K_ + k0 + t] = d;
  }
}

// ---------------------------------------------------------------------------
// Top-8 candidates per b from approx dists (iterative selection).
__global__ void k_top8(const float* __restrict__ dists, int* __restrict__ topi) {
  __shared__ float ds[F_ * K_];
  __shared__ float bv[256];
  __shared__ int bi_s[256];
  const int b = blockIdx.x, t = threadIdx.x;
  for (int j = t; j < F_ * K_; j += 256) ds[j] = dists[b * (F_ * K_) + j];
  __syncthreads();
  for (int pass = 0; pass < 8; ++pass) {
    float best = 3.4e38f; int bi = 0;
    for (int j = t; j < F_ * K_; j += 256) {
      const float dv = ds[j];
      if (dv < best) { best = dv; bi = j; }
    }
    bv[t] = best; bi_s[t] = bi;
    __syncthreads();
    for (int s = 128; s > 0; s >>= 1) {
      if (t < s) {
        const float ov = bv[t + s]; const int oi = bi_s[t + s];
        if (ov < bv[t] || (ov == bv[t] && oi < bi_s[t])) { bv[t] = ov; bi_s[t] = oi; }
      }
      __syncthreads();
    }
    if (t == 0) { topi[b * 8 + pass] = bi_s[0]; ds[bi_s[0]] = 3.4e38f; }
    __syncthreads();
  }
}

// ---------------------------------------------------------------------------
// R15: exact rescore, 256 blocks x 512 threads. Block (b, half) owns 4
// candidates; thread-group g (= t>>8, 256 threads) owns 2 of them. Weights
// read 2x per b (4x less than old k_rescore). Per-candidate fma chain order
// identical to R14/k_rescore (sequential i/jj, q within float4) -> numerics
// match. Best-of-4 (lexicographic (d, idx) min) + winner cw row -> global;
// k_finw combines the two halves.
#define NCL 2
__global__ __launch_bounds__(512) void k_resfin(
    const float* __restrict__ u, const float* __restrict__ v,
    const float* __restrict__ W1, const float* __restrict__ b1,
    const float* __restrict__ W2, const float* __restrict__ b2,
    const float* __restrict__ Wout, const float* __restrict__ bout,
    const float* __restrict__ cb, const float* __restrict__ xhat,
    const float* __restrict__ x, const int* __restrict__ topi,
    float* __restrict__ resc2, int* __restrict__ iwin2,
    float* __restrict__ cwhalf) {
  __shared__ float hs4[4][H_ + 4];      // 4160 B (rows 16B-aligned)
  __shared__ float hms4[4][HFF_ + 4];   // 8256 B
  __shared__ float cw4[4][H_ + 4];      // 4160 B
  __shared__ float redw[8][NCL];
  __shared__ int   sel_sh;

  const int blk = blockIdx.x;
  const int b = blk >> 1, half = blk & 1;
  const int t = threadIdx.x;
  const int g = t >> 8, tloc = t & 255;
  const int wave = t >> 6, lane = t & 63;
  const int cbase = half * 4;

  int kc[NCL], bfc[NCL];
  #pragma unroll
  for (int cl = 0; cl < NCL; ++cl) {
    const int ix = topi[b * 8 + cbase + g * 2 + cl];
    kc[cl] = ix & 255;
    bfc[cl] = b * F_ + (ix >> 8);
  }

  // hs init: hs[2g+cl][tloc] = u[k][tloc] + v[bf][tloc]
  #pragma unroll
  for (int cl = 0; cl < NCL; ++cl)
    hs4[g * 2 + cl][tloc] = u[kc[cl] * H_ + tloc] + v[bfc[cl] * H_ + tloc];
  __syncthreads();

  #pragma unroll 1
  for (int l = 0; l < 2; ++l) {
    const float* W1l = W1 + l * (H_ * HFF_);
    const float* W2l = W2 + l * (HFF_ * H_);

    // ---- hm = relu(h @ W1 + b1): thread owns outputs tloc and tloc+256 ----
    float a0[NCL], a1[NCL];
    {
      const float bb0 = b1[l * HFF_ + tloc], bb1 = b1[l * HFF_ + 256 + tloc];
      #pragma unroll
      for (int cl = 0; cl < NCL; ++cl) { a0[cl] = bb0; a1[cl] = bb1; }
    }
    #pragma unroll 2
    for (int i = 0; i < H_; i += 4) {
      float4 hv[NCL];
      #pragma unroll
      for (int cl = 0; cl < NCL; ++cl) hv[cl] = *(const float4*)&hs4[g * 2 + cl][i];
      #pragma unroll
      for (int q = 0; q < 4; ++q) {
        const float w0 = W1l[(i + q) * HFF_ + tloc];
        const float w1 = W1l[(i + q) * HFF_ + 256 + tloc];
        #pragma unroll
        for (int cl = 0; cl < NCL; ++cl) {
          const float h = ((const float*)&hv[cl])[q];
          a0[cl] = fmaf(h, w0, a0[cl]);
          a1[cl] = fmaf(h, w1, a1[cl]);
        }
      }
    }
    #pragma unroll
    for (int cl = 0; cl < NCL; ++cl) {
      hms4[g * 2 + cl][tloc] = fmaxf(a0[cl], 0.f);
      hms4[g * 2 + cl][tloc + 256] = fmaxf(a1[cl], 0.f);
    }
    __syncthreads();

    // ---- h = h + hm @ W2 + b2 ----
    float hn[NCL];
    {
      const float bb2 = b2[l * H_ + tloc];
      #pragma unroll
      for (int cl = 0; cl < NCL; ++cl) hn[cl] = hs4[g * 2 + cl][tloc] + bb2;
    }
    #pragma unroll 2
    for (int jj = 0; jj < HFF_; jj += 4) {
      float4 hv[NCL];
      #pragma unroll
      for (int cl = 0; cl < NCL; ++cl) hv[cl] = *(const float4*)&hms4[g * 2 + cl][jj];
      #pragma unroll
      for (int q = 0; q < 4; ++q) {
        const float w = W2l[(jj + q) * H_ + tloc];
        #pragma unroll
        for (int cl = 0; cl < NCL; ++cl)
          hn[cl] = fmaf(((const float*)&hv[cl])[q], w, hn[cl]);
      }
    }
    __syncthreads();   // all reads of hs4/hms4 done before overwrite
    #pragma unroll
    for (int cl = 0; cl < NCL; ++cl) hs4[g * 2 + cl][tloc] = hn[cl];
    __syncthreads();
  }

  // ---- cw = h @ Wout + bout + cb + xhat; distance partials ----
  float cw[NCL];
  {
    const float bo = bout[tloc];
    #pragma unroll
    for (int cl = 0; cl < NCL; ++cl)
      cw[cl] = bo + cb[kc[cl] * D_ + tloc] + xhat[bfc[cl] * D_ + tloc];
  }
  #pragma unroll 2
  for (int i = 0; i < H_; i += 4) {
    float4 hv[NCL];
    #pragma unroll
    for (int cl = 0; cl < NCL; ++cl) hv[cl] = *(const float4*)&hs4[g * 2 + cl][i];
    #pragma unroll
    for (int q = 0; q < 4; ++q) {
      const float w = Wout[(i + q) * D_ + tloc];
      #pragma unroll
      for (int cl = 0; cl < NCL; ++cl)
        cw[cl] = fmaf(((const float*)&hv[cl])[q], w, cw[cl]);
    }
  }

  const float xx = x[b * D_ + tloc];
  #pragma unroll
  for (int cl = 0; cl < NCL; ++cl) {
    cw4[g * 2 + cl][tloc] = cw[cl];
    float vsum = cw[cl] * (cw[cl] - 2.f * xx);
    vsum += __shfl_xor(vsum, 1, 64);
    vsum += __shfl_xor(vsum, 2, 64);
    vsum += __shfl_xor(vsum, 4, 64);
    vsum += __shfl_xor(vsum, 8, 64);
    vsum += __shfl_xor(vsum, 16, 64);
    vsum += __shfl_xor(vsum, 32, 64);
    if (lane == 0) redw[wave][cl] = vsum;
  }
  __syncthreads();
  if (t == 0) {
    float bd = 3.4e38f; int bidx = 1 << 30; int bc = 0;
    #pragma unroll
    for (int c = 0; c < 4; ++c) {
      const int gg = c >> 1, cl = c & 1;
      const float d = redw[gg * 4 + 0][cl] + redw[gg * 4 + 1][cl] +
                      redw[gg * 4 + 2][cl] + redw[gg * 4 + 3][cl];
      const int ix = topi[b * 8 + cbase + c];
      if (d < bd || (d == bd && ix < bidx)) { bd = d; bidx = ix; bc = c; }
    }
    resc2[blk] = bd;
    iwin2[blk] = bidx;
    sel_sh = bc;
  }
  __syncthreads();
  if (t < 256) cwhalf[blk * 256 + t] = cw4[sel_sh][t];
}

// ---------------------------------------------------------------------------
// R15: combine the two halves' winners; write output.
__global__ void k_finw(const float* __restrict__ resc2, const int* __restrict__ iwin2,
                       const float* __restrict__ cwhalf, const int* __restrict__ codes,
                       float* __restrict__ out) {
  const int b = blockIdx.x, t = threadIdx.x;
  const float d0 = resc2[b * 2], d1 = resc2[b * 2 + 1];
  const int i0 = iwin2[b * 2], i1 = iwin2[b * 2 + 1];
  const int sel = (d1 < d0 || (d1 == d0 && i1 < i0)) ? 1 : 0;
  out[b * D_ + t] = cwhalf[(b * 2 + sel) * 256 + t];
  if (t < 2)
    out[B_ * D_ + t * B_ + b] = (float)codes[t * B_ + b];
  else if (t == 2)
    out[B_ * D_ + 2 * B_ + b] = (float)(sel ? i1 : i0);
}

// ---------------------------------------------------------------------------
extern "C" void kernel_launch(void* const* d_in, const int* in_sizes, int n_in,
                              void* d_out, int out_size, void* d_ws, size_t ws_size,
                              hipStream_t stream) {
  const float* x    = (const float*)d_in[0];
  const float* xhat = (const float*)d_in[1];
  const int*   codes= (const int*)d_in[2];
  const float* cb   = (const float*)d_in[3];
  const float* Win  = (const float*)d_in[4];
  const float* bin  = (const float*)d_in[5];
  const float* Wcat = (const float*)d_in[6];
  const float* bcat = (const float*)d_in[7];
  const float* W1   = (const float*)d_in[8];
  const float* b1   = (const float*)d_in[9];
  const float* W2   = (const float*)d_in[10];
  const float* b2   = (const float*)d_in[11];
  const float* Wout = (const float*)d_in[12];
  const float* bout = (const float*)d_in[13];
  float* out = (float*)d_out;

  float* u     = (float*)d_ws;                  // 65536 f (h0 eliminated)
  float* v     = u + K_ * H_;                   // 262144 f
  float* dists = v + B_ * F_ * H_;              // 262144 f
  float* resc  = dists + B_ * F_ * K_;          // 1024 f
  int*   topi  = (int*)(resc + 1024);           // 1024 i
  int*   pad   = topi + 1024;                   // 128 pad (keeps 16B align)
  _Float16* w1f  = (_Float16*)(pad + 128);      // 2*H*HFF halves
  _Float16* w2f  = w1f + 2 * H_ * HFF_;
  _Float16* wof  = w2f + 2 * HFF_ * H_;

  // R15 scratch: resc2 (256 f) + iwin2 (256 i) carved from resc region;
  // cwhalf (256*256 f) aliases dists (dead after k_top8).
  float* resc2  = resc;
  int*   iwin2  = (int*)(resc + 256);
  float* cwhalf = dists;

  k_prep<<<K_ + B_ * F_ + 2304, 256, 0, stream>>>(cb, Win, bin, Wcat, bcat, xhat,
                                                  W1, W2, Wout, u, v, w1f, w2f, wof);

  k_main<<<B_ * F_ * (K_ / RT), 256, 0, stream>>>(u, v, w1f, b1, w2f, b2,
                                                  wof, bout, cb, xhat, x, dists);
  k_top8<<<B_, 256, 0, stream>>>(dists, topi);
  k_resfin<<<2 * B_, 512, 0, stream>>>(u, v, W1, b1, W2, b2, Wout, bout, cb, xhat,
                                       x, topi, resc2, iwin2, cwhalf);
  k_finw<<<B_, 256, 0, stream>>>(resc2, iwin2, cwhalf, codes, out);
}

// Round 7
// 521.890 us; speedup vs baseline: 1.2151x; 1.0368x over previous
//
#include <hip/hip_runtime.h>
#include <hip/hip_bf16.h>

// Shapes (fixed): B=128, F=8, K=256, D=256, H=256, HFF=512, L=2, M_PREV=2
#define B_   128
#define F_   8
#define K_   256
#define D_   256
#define H_   256
#define HFF_ 512
#define RT   64   // candidates per block

typedef _Float16 half8  __attribute__((ext_vector_type(8)));  // f16x8 MFMA frag
typedef _Float16 half4v __attribute__((ext_vector_type(4)));
typedef float floatx4   __attribute__((ext_vector_type(4)));  // MFMA acc

#define MFMAH(a,b,c) __builtin_amdgcn_mfma_f32_16x16x32_f16(a,b,c,0,0,0)

// R16: k_main = R9 config + s_setprio around MFMA clusters (independent
// 3-blocks/CU regime = m191 attn-like). k_prep: 4-acc ILP on the serial
// fma chains (latency-bound, not compute-bound). k_top8: 512 threads.
// k_resfin/k_finw unchanged from verified R15.
#define HA_S  260
#define HMA_S 132

// ---------------------------------------------------------------------------
// Fused prep — one launch for (h0->u), v, and the fp16 weight shuffle.
__global__ void k_prep(const float* __restrict__ cb, const float* __restrict__ Win,
                       const float* __restrict__ bin, const float* __restrict__ Wcat,
                       const float* __restrict__ bcat, const float* __restrict__ xhat,
                       const float* __restrict__ W1, const float* __restrict__ W2,
                       const float* __restrict__ Wout,
                       float* __restrict__ u, float* __restrict__ v,
                       _Float16* __restrict__ w1f, _Float16* __restrict__ w2f,
                       _Float16* __restrict__ wof) {
  const int blk = blockIdx.x, t = threadIdx.x;
  if (blk < K_) {
    __shared__ float row[D_];
    __shared__ float h0row[H_];
    row[t] = cb[blk * D_ + t];
    __syncthreads();
    // R16: 4 independent acc chains (was 1) — latency-bound fix
    float a0 = 0.f, a1 = 0.f, a2 = 0.f, a3 = 0.f;
    #pragma unroll 4
    for (int i = 0; i < 64; ++i) {
      a0 = fmaf(row[i      ], Win[(i      ) * H_ + t], a0);
      a1 = fmaf(row[i +  64], Win[(i +  64) * H_ + t], a1);
      a2 = fmaf(row[i + 128], Win[(i + 128) * H_ + t], a2);
      a3 = fmaf(row[i + 192], Win[(i + 192) * H_ + t], a3);
    }
    h0row[t] = bin[t] + ((a0 + a1) + (a2 + a3));
    __syncthreads();
    float c0 = 0.f, c1 = 0.f, c2 = 0.f, c3 = 0.f;
    #pragma unroll 4
    for (int i = 0; i < 64; ++i) {
      c0 = fmaf(h0row[i      ], Wcat[(i      ) * H_ + t], c0);
      c1 = fmaf(h0row[i +  64], Wcat[(i +  64) * H_ + t], c1);
      c2 = fmaf(h0row[i + 128], Wcat[(i + 128) * H_ + t], c2);
      c3 = fmaf(h0row[i + 192], Wcat[(i + 192) * H_ + t], c3);
    }
    u[blk * H_ + t] = (c0 + c1) + (c2 + c3);
  } else if (blk < K_ + B_ * F_) {
    __shared__ float row2[D_];
    const int bf = blk - K_;
    row2[t] = xhat[bf * D_ + t];
    __syncthreads();
    float a0 = 0.f, a1 = 0.f, a2 = 0.f, a3 = 0.f;
    #pragma unroll 4
    for (int i = 0; i < 64; ++i) {
      a0 = fmaf(row2[i      ], Wcat[(H_ + i      ) * H_ + t], a0);
      a1 = fmaf(row2[i +  64], Wcat[(H_ + i +  64) * H_ + t], a1);
      a2 = fmaf(row2[i + 128], Wcat[(H_ + i + 128) * H_ + t], a2);
      a3 = fmaf(row2[i + 192], Wcat[(H_ + i + 192) * H_ + t], a3);
    }
    v[bf * H_ + t] = bcat[t] + ((a0 + a1) + (a2 + a3));
  } else {
    const int e = (blk - (K_ + B_ * F_)) * 256 + t;
    const float* src; _Float16* dst; int N, NT, le;
    if (e < 262144) {
      const int layer = e >> 17; le = e & 131071;
      src = W1 + layer * (H_ * HFF_); dst = w1f + layer * (H_ * HFF_);
      N = HFF_; NT = 32;
    } else if (e < 524288) {
      const int e2 = e - 262144;
      const int layer = e2 >> 17; le = e2 & 131071;
      src = W2 + layer * (HFF_ * H_); dst = w2f + layer * (HFF_ * H_);
      N = H_; NT = 16;
    } else {
      le = e - 524288; src = Wout; dst = wof; N = D_; NT = 16;
    }
    const int jj = le & 7, lane = (le >> 3) & 63, r = le >> 9;
    const int ntile = r % NT, kstep = r / NT;
    const int row = kstep * 32 + (lane >> 4) * 8 + jj;
    const int colc = ntile * 16 + (lane & 15);
    dst[le] = (_Float16)src[row * N + colc];
  }
}

// ---------------------------------------------------------------------------
// MFMA main kernel (R9 verified config + setprio): fp16, 64 cand/block.
__global__ __launch_bounds__(256, 3) void k_main(
    const float* __restrict__ u, const float* __restrict__ v,
    const _Float16* __restrict__ w1f, const float* __restrict__ b1,
    const _Float16* __restrict__ w2f, const float* __restrict__ b2,
    const _Float16* __restrict__ woutf, const float* __restrict__ bout,
    const float* __restrict__ cb, const float* __restrict__ xhat,
    const float* __restrict__ x, float* __restrict__ dists) {
  __shared__ _Float16 hA[64][HA_S];    // 33280 B
  __shared__ _Float16 hmA[64][HMA_S];  // 16896 B
  __shared__ float x_s[D_], xh_s[D_];  // 2048 B
  __shared__ float dist_s[4][64];      // 1024 B

  const int t = threadIdx.x;
  const int blk = blockIdx.x;
  const int bf = blk >> 2, k0 = (blk & 3) << 6;
  const int b = bf >> 3, f = bf & 7;
  const int wave = t >> 6, lane = t & 63;
  const int col = lane & 15, quad = lane >> 4;
  const int lane8 = lane * 8;

  x_s[t]  = x[b * D_ + t];
  xh_s[t] = xhat[bf * D_ + t];

  // stage h = u + v -> fp16, packed 16B writes
  {
    const int r = t >> 2, c0 = (t & 3) * 64;
    const float* up = u + (k0 + r) * H_ + c0;
    const float* vp = v + bf * H_ + c0;
    #pragma unroll
    for (int j = 0; j < 64; j += 8) {
      float4 uA = *(const float4*)(up + j);
      float4 vA = *(const float4*)(vp + j);
      float4 uB = *(const float4*)(up + j + 4);
      float4 vB = *(const float4*)(vp + j + 4);
      half8 hv8;
      hv8[0] = (_Float16)(uA.x + vA.x); hv8[1] = (_Float16)(uA.y + vA.y);
      hv8[2] = (_Float16)(uA.z + vA.z); hv8[3] = (_Float16)(uA.w + vA.w);
      hv8[4] = (_Float16)(uB.x + vB.x); hv8[5] = (_Float16)(uB.y + vB.y);
      hv8[6] = (_Float16)(uB.z + vB.z); hv8[7] = (_Float16)(uB.w + vB.w);
      *(half8*)&hA[r][c0 + j] = hv8;
    }
  }
  __syncthreads();

  const floatx4 zero4 = {0.f, 0.f, 0.f, 0.f};

  #pragma unroll 1
  for (int l = 0; l < 2; ++l) {
    const _Float16* w1_l = w1f + l * (H_ * HFF_);
    const _Float16* w2_l = w2f + l * (HFF_ * H_);
    const float* b1l = b1 + l * HFF_;
    const float* b2l = b2 + l * H_;

    floatx4 acc2[4][4];   // [out-feature tile][candidate-row tile]
    #pragma unroll
    for (int mt = 0; mt < 4; ++mt)
      #pragma unroll
      for (int nt = 0; nt < 4; ++nt) acc2[mt][nt] = zero4;

    #pragma unroll 1
    for (int ch = 0; ch < 4; ++ch) {
      // ---- GEMM1': hm' = relu(W1[:,chunk]^T @ h^T + b1) ----
      floatx4 acc1[2][4];
      #pragma unroll
      for (int mt = 0; mt < 2; ++mt)
        #pragma unroll
        for (int nt = 0; nt < 4; ++nt) acc1[mt][nt] = zero4;

      const _Float16* w1_b = w1_l + (ch * 8 + wave * 2) * 512 + lane8;

      __builtin_amdgcn_s_setprio(1);
      #pragma unroll 4
      for (int ks = 0; ks < 8; ++ks) {
        half8 b0 = *(const half8*)&hA[col][ks * 32 + quad * 8];
        half8 b1v = *(const half8*)&hA[16 + col][ks * 32 + quad * 8];
        half8 b2v = *(const half8*)&hA[32 + col][ks * 32 + quad * 8];
        half8 b3v = *(const half8*)&hA[48 + col][ks * 32 + quad * 8];
        const int ko = ks * 32 * 512;
        #pragma unroll
        for (int mt = 0; mt < 2; ++mt) {
          half8 aw = *(const half8*)(w1_b + ko + mt * 512);
          acc1[mt][0] = MFMAH(aw, b0, acc1[mt][0]);
          acc1[mt][1] = MFMAH(aw, b1v, acc1[mt][1]);
          acc1[mt][2] = MFMAH(aw, b2v, acc1[mt][2]);
          acc1[mt][3] = MFMAH(aw, b3v, acc1[mt][3]);
        }
      }
      __builtin_amdgcn_s_setprio(0);
      // bias + relu -> fp16, packed 8B stores (4 consecutive features/lane)
      #pragma unroll
      for (int mt = 0; mt < 2; ++mt) {
        const int floc = (wave * 2 + mt) * 16 + quad * 4;
        float4 bb = *(const float4*)&b1l[ch * 128 + floc];
        #pragma unroll
        for (int nt = 0; nt < 4; ++nt) {
          const int row = nt * 16 + col;
          half4v nh;
          #pragma unroll
          for (int p = 0; p < 4; ++p)
            nh[p] = (_Float16)fmaxf(acc1[mt][nt][p] + ((const float*)&bb)[p], 0.f);
          *(half4v*)&hmA[row][floc] = nh;
        }
      }
      __syncthreads();

      // ---- GEMM2': acc2 += W2[chunk,:]^T @ hm'^T ----
      const _Float16* w2_b = w2_l + (ch * 64 + wave * 4) * 512 + lane8;
      __builtin_amdgcn_s_setprio(1);
      #pragma unroll 2
      for (int ks = 0; ks < 4; ++ks) {
        half8 b0 = *(const half8*)&hmA[col][ks * 32 + quad * 8];
        half8 b1v = *(const half8*)&hmA[16 + col][ks * 32 + quad * 8];
        half8 b2v = *(const half8*)&hmA[32 + col][ks * 32 + quad * 8];
        half8 b3v = *(const half8*)&hmA[48 + col][ks * 32 + quad * 8];
        const int ko = ks * 16 * 512;
        #pragma unroll
        for (int mt = 0; mt < 4; ++mt) {
          half8 aw = *(const half8*)(w2_b + ko + mt * 512);
          acc2[mt][0] = MFMAH(aw, b0, acc2[mt][0]);
          acc2[mt][1] = MFMAH(aw, b1v, acc2[mt][1]);
          acc2[mt][2] = MFMAH(aw, b2v, acc2[mt][2]);
          acc2[mt][3] = MFMAH(aw, b3v, acc2[mt][3]);
        }
      }
      __builtin_amdgcn_s_setprio(0);
      __syncthreads();
    }

    // ---- residual: h += acc2 + b2, packed 8B read/modify/write ----
    #pragma unroll
    for (int mt = 0; mt < 4; ++mt) {
      const int feat0 = (wave * 4 + mt) * 16 + quad * 4;
      float4 bb = *(const float4*)&b2l[feat0];
      #pragma unroll
      for (int nt = 0; nt < 4; ++nt) {
        const int row = nt * 16 + col;
        half4v oh = *(half4v*)&hA[row][feat0];
        half4v nh;
        #pragma unroll
        for (int p = 0; p < 4; ++p)
          nh[p] = (_Float16)((float)oh[p] + acc2[mt][nt][p] + ((const float*)&bb)[p]);
        *(half4v*)&hA[row][feat0] = nh;
      }
    }
    __syncthreads();
  }

  // ---- GEMM3': cw' = Wout^T @ h^T (+bout+cb+xhat), then distance ----
  floatx4 acc3[4][4];
  #pragma unroll
  for (int mt = 0; mt < 4; ++mt)
    #pragma unroll
    for (int nt = 0; nt < 4; ++nt) acc3[mt][nt] = zero4;

  const _Float16* wo_b = woutf + (wave * 4) * 512 + lane8;
  __builtin_amdgcn_s_setprio(1);
  #pragma unroll 2
  for (int ks = 0; ks < 8; ++ks) {
    half8 b0 = *(const half8*)&hA[col][ks * 32 + quad * 8];
    half8 b1v = *(const half8*)&hA[16 + col][ks * 32 + quad * 8];
    half8 b2v = *(const half8*)&hA[32 + col][ks * 32 + quad * 8];
    half8 b3v = *(const half8*)&hA[48 + col][ks * 32 + quad * 8];
    const int ko = ks * 16 * 512;
    #pragma unroll
    for (int mt = 0; mt < 4; ++mt) {
      half8 aw = *(const half8*)(wo_b + ko + mt * 512);
      acc3[mt][0] = MFMAH(aw, b0, acc3[mt][0]);
      acc3[mt][1] = MFMAH(aw, b1v, acc3[mt][1]);
      acc3[mt][2] = MFMAH(aw, b2v, acc3[mt][2]);
      acc3[mt][3] = MFMAH(aw, b3v, acc3[mt][3]);
    }
  }
  __builtin_amdgcn_s_setprio(0);

  float s[4] = {0.f, 0.f, 0.f, 0.f};
  #pragma unroll
  for (int mt = 0; mt < 4; ++mt) {
    const int d0 = (wave * 4 + mt) * 16 + quad * 4;
    float4 bo = *(const float4*)&bout[d0];
    float4 xv = *(const float4*)&x_s[d0];
    float4 xh4 = *(const float4*)&xh_s[d0];
    #pragma unroll
    for (int nt = 0; nt < 4; ++nt) {
      float4 cbv = *(const float4*)&cb[(k0 + nt * 16 + col) * D_ + d0];
      #pragma unroll
      for (int p = 0; p < 4; ++p) {
        float base = ((const float*)&bo)[p] + ((const float*)&xh4)[p];
        float xx = ((const float*)&xv)[p];
        float cw = acc3[mt][nt][p] + base + ((const float*)&cbv)[p];
        s[nt] += cw * (cw - 2.f * xx);   // -||x||^2 const: argmin-invariant
      }
    }
  }
  #pragma unroll
  for (int nt = 0; nt < 4; ++nt) {
    s[nt] += __shfl_xor(s[nt], 16, 64);
    s[nt] += __shfl_xor(s[nt], 32, 64);
  }
  if (quad == 0) {
    #pragma unroll
    for (int nt = 0; nt < 4; ++nt)
      dist_s[wave][nt * 16 + col] = s[nt];
  }
  __syncthreads();
  if (t < 64) {
    float d = dist_s[0][t] + dist_s[1][t] + dist_s[2][t] + dist_s[3][t];
    dists[b * (F_ * K_) + f * K_ + k0 + t] = d;
  }
}

// ---------------------------------------------------------------------------
// Top-8 candidates per b from approx dists (iterative selection).
// R16: 512 threads (scan 4/thread instead of 8); identical tie-break.
__global__ void k_top8(const float* __restrict__ dists, int* __restrict__ topi) {
  __shared__ float ds[F_ * K_];
  __shared__ float bv[512];
  __shared__ int bi_s[512];
  const int b = blockIdx.x, t = threadIdx.x;
  for (int j = t; j < F_ * K_; j += 512) ds[j] = dists[b * (F_ * K_) + j];
  __syncthreads();
  for (int pass = 0; pass < 8; ++pass) {
    float best = 3.4e38f; int bi = 0;
    for (int j = t; j < F_ * K_; j += 512) {
      const float dv = ds[j];
      if (dv < best) { best = dv; bi = j; }
    }
    bv[t] = best; bi_s[t] = bi;
    __syncthreads();
    for (int s = 256; s > 0; s >>= 1) {
      if (t < s) {
        const float ov = bv[t + s]; const int oi = bi_s[t + s];
        if (ov < bv[t] || (ov == bv[t] && oi < bi_s[t])) { bv[t] = ov; bi_s[t] = oi; }
      }
      __syncthreads();
    }
    if (t == 0) { topi[b * 8 + pass] = bi_s[0]; ds[bi_s[0]] = 3.4e38f; }
    __syncthreads();
  }
}

// ---------------------------------------------------------------------------
// R15: exact rescore, 256 blocks x 512 threads. Block (b, half) owns 4
// candidates; thread-group g (= t>>8, 256 threads) owns 2 of them. Weights
// read 2x per b. Per-candidate fma chain order identical to old k_rescore.
#define NCL 2
__global__ __launch_bounds__(512) void k_resfin(
    const float* __restrict__ u, const float* __restrict__ v,
    const float* __restrict__ W1, const float* __restrict__ b1,
    const float* __restrict__ W2, const float* __restrict__ b2,
    const float* __restrict__ Wout, const float* __restrict__ bout,
    const float* __restrict__ cb, const float* __restrict__ xhat,
    const float* __restrict__ x, const int* __restrict__ topi,
    float* __restrict__ resc2, int* __restrict__ iwin2,
    float* __restrict__ cwhalf) {
  __shared__ float hs4[4][H_ + 4];      // 4160 B (rows 16B-aligned)
  __shared__ float hms4[4][HFF_ + 4];   // 8256 B
  __shared__ float cw4[4][H_ + 4];      // 4160 B
  __shared__ float redw[8][NCL];
  __shared__ int   sel_sh;

  const int blk = blockIdx.x;
  const int b = blk >> 1, half = blk & 1;
  const int t = threadIdx.x;
  const int g = t >> 8, tloc = t & 255;
  const int wave = t >> 6, lane = t & 63;
  const int cbase = half * 4;

  int kc[NCL], bfc[NCL];
  #pragma unroll
  for (int cl = 0; cl < NCL; ++cl) {
    const int ix = topi[b * 8 + cbase + g * 2 + cl];
    kc[cl] = ix & 255;
    bfc[cl] = b * F_ + (ix >> 8);
  }

  // hs init: hs[2g+cl][tloc] = u[k][tloc] + v[bf][tloc]
  #pragma unroll
  for (int cl = 0; cl < NCL; ++cl)
    hs4[g * 2 + cl][tloc] = u[kc[cl] * H_ + tloc] + v[bfc[cl] * H_ + tloc];
  __syncthreads();

  #pragma unroll 1
  for (int l = 0; l < 2; ++l) {
    const float* W1l = W1 + l * (H_ * HFF_);
    const float* W2l = W2 + l * (HFF_ * H_);

    // ---- hm = relu(h @ W1 + b1): thread owns outputs tloc and tloc+256 ----
    float a0[NCL], a1[NCL];
    {
      const float bb0 = b1[l * HFF_ + tloc], bb1 = b1[l * HFF_ + 256 + tloc];
      #pragma unroll
      for (int cl = 0; cl < NCL; ++cl) { a0[cl] = bb0; a1[cl] = bb1; }
    }
    #pragma unroll 2
    for (int i = 0; i < H_; i += 4) {
      float4 hv[NCL];
      #pragma unroll
      for (int cl = 0; cl < NCL; ++cl) hv[cl] = *(const float4*)&hs4[g * 2 + cl][i];
      #pragma unroll
      for (int q = 0; q < 4; ++q) {
        const float w0 = W1l[(i + q) * HFF_ + tloc];
        const float w1 = W1l[(i + q) * HFF_ + 256 + tloc];
        #pragma unroll
        for (int cl = 0; cl < NCL; ++cl) {
          const float h = ((const float*)&hv[cl])[q];
          a0[cl] = fmaf(h, w0, a0[cl]);
          a1[cl] = fmaf(h, w1, a1[cl]);
        }
      }
    }
    #pragma unroll
    for (int cl = 0; cl < NCL; ++cl) {
      hms4[g * 2 + cl][tloc] = fmaxf(a0[cl], 0.f);
      hms4[g * 2 + cl][tloc + 256] = fmaxf(a1[cl], 0.f);
    }
    __syncthreads();

    // ---- h = h + hm @ W2 + b2 ----
    float hn[NCL];
    {
      const float bb2 = b2[l * H_ + tloc];
      #pragma unroll
      for (int cl = 0; cl < NCL; ++cl) hn[cl] = hs4[g * 2 + cl][tloc] + bb2;
    }
    #pragma unroll 2
    for (int jj = 0; jj < HFF_; jj += 4) {
      float4 hv[NCL];
      #pragma unroll
      for (int cl = 0; cl < NCL; ++cl) hv[cl] = *(const float4*)&hms4[g * 2 + cl][jj];
      #pragma unroll
      for (int q = 0; q < 4; ++q) {
        const float w = W2l[(jj + q) * H_ + tloc];
        #pragma unroll
        for (int cl = 0; cl < NCL; ++cl)
          hn[cl] = fmaf(((const float*)&hv[cl])[q], w, hn[cl]);
      }
    }
    __syncthreads();   // all reads of hs4/hms4 done before overwrite
    #pragma unroll
    for (int cl = 0; cl < NCL; ++cl) hs4[g * 2 + cl][tloc] = hn[cl];
    __syncthreads();
  }

  // ---- cw = h @ Wout + bout + cb + xhat; distance partials ----
  float cw[NCL];
  {
    const float bo = bout[tloc];
    #pragma unroll
    for (int cl = 0; cl < NCL; ++cl)
      cw[cl] = bo + cb[kc[cl] * D_ + tloc] + xhat[bfc[cl] * D_ + tloc];
  }
  #pragma unroll 2
  for (int i = 0; i < H_; i += 4) {
    float4 hv[NCL];
    #pragma unroll
    for (int cl = 0; cl < NCL; ++cl) hv[cl] = *(const float4*)&hs4[g * 2 + cl][i];
    #pragma unroll
    for (int q = 0; q < 4; ++q) {
      const float w = Wout[(i + q) * D_ + tloc];
      #pragma unroll
      for (int cl = 0; cl < NCL; ++cl)
        cw[cl] = fmaf(((const float*)&hv[cl])[q], w, cw[cl]);
    }
  }

  const float xx = x[b * D_ + tloc];
  #pragma unroll
  for (int cl = 0; cl < NCL; ++cl) {
    cw4[g * 2 + cl][tloc] = cw[cl];
    float vsum = cw[cl] * (cw[cl] - 2.f * xx);
    vsum += __shfl_xor(vsum, 1, 64);
    vsum += __shfl_xor(vsum, 2, 64);
    vsum += __shfl_xor(vsum, 4, 64);
    vsum += __shfl_xor(vsum, 8, 64);
    vsum += __shfl_xor(vsum, 16, 64);
    vsum += __shfl_xor(vsum, 32, 64);
    if (lane == 0) redw[wave][cl] = vsum;
  }
  __syncthreads();
  if (t == 0) {
    float bd = 3.4e38f; int bidx = 1 << 30; int bc = 0;
    #pragma unroll
    for (int c = 0; c < 4; ++c) {
      const int gg = c >> 1, cl = c & 1;
      const float d = redw[gg * 4 + 0][cl] + redw[gg * 4 + 1][cl] +
                      redw[gg * 4 + 2][cl] + redw[gg * 4 + 3][cl];
      const int ix = topi[b * 8 + cbase + c];
      if (d < bd || (d == bd && ix < bidx)) { bd = d; bidx = ix; bc = c; }
    }
    resc2[blk] = bd;
    iwin2[blk] = bidx;
    sel_sh = bc;
  }
  __syncthreads();
  if (t < 256) cwhalf[blk * 256 + t] = cw4[sel_sh][t];
}

// ---------------------------------------------------------------------------
// Combine the two halves' winners; write output.
__global__ void k_finw(const float* __restrict__ resc2, const int* __restrict__ iwin2,
                       const float* __restrict__ cwhalf, const int* __restrict__ codes,
                       float* __restrict__ out) {
  const int b = blockIdx.x, t = threadIdx.x;
  const float d0 = resc2[b * 2], d1 = resc2[b * 2 + 1];
  const int i0 = iwin2[b * 2], i1 = iwin2[b * 2 + 1];
  const int sel = (d1 < d0 || (d1 == d0 && i1 < i0)) ? 1 : 0;
  out[b * D_ + t] = cwhalf[(b * 2 + sel) * 256 + t];
  if (t < 2)
    out[B_ * D_ + t * B_ + b] = (float)codes[t * B_ + b];
  else if (t == 2)
    out[B_ * D_ + 2 * B_ + b] = (float)(sel ? i1 : i0);
}

// ---------------------------------------------------------------------------
extern "C" void kernel_launch(void* const* d_in, const int* in_sizes, int n_in,
                              void* d_out, int out_size, void* d_ws, size_t ws_size,
                              hipStream_t stream) {
  const float* x    = (const float*)d_in[0];
  const float* xhat = (const float*)d_in[1];
  const int*   codes= (const int*)d_in[2];
  const float* cb   = (const float*)d_in[3];
  const float* Win  = (const float*)d_in[4];
  const float* bin  = (const float*)d_in[5];
  const float* Wcat = (const float*)d_in[6];
  const float* bcat = (const float*)d_in[7];
  const float* W1   = (const float*)d_in[8];
  const float* b1   = (const float*)d_in[9];
  const float* W2   = (const float*)d_in[10];
  const float* b2   = (const float*)d_in[11];
  const float* Wout = (const float*)d_in[12];
  const float* bout = (const float*)d_in[13];
  float* out = (float*)d_out;

  float* u     = (float*)d_ws;                  // 65536 f (h0 eliminated)
  float* v     = u + K_ * H_;                   // 262144 f
  float* dists = v + B_ * F_ * H_;              // 262144 f
  float* resc  = dists + B_ * F_ * K_;          // 1024 f
  int*   topi  = (int*)(resc + 1024);           // 1024 i
  int*   pad   = topi + 1024;                   // 128 pad (keeps 16B align)
  _Float16* w1f  = (_Float16*)(pad + 128);      // 2*H*HFF halves
  _Float16* w2f  = w1f + 2 * H_ * HFF_;
  _Float16* wof  = w2f + 2 * HFF_ * H_;

  // scratch: resc2 (256 f) + iwin2 (256 i) carved from resc region;
  // cwhalf (256*256 f) aliases dists (dead after k_top8).
  float* resc2  = resc;
  int*   iwin2  = (int*)(resc + 256);
  float* cwhalf = dists;

  k_prep<<<K_ + B_ * F_ + 2304, 256, 0, stream>>>(cb, Win, bin, Wcat, bcat, xhat,
                                                  W1, W2, Wout, u, v, w1f, w2f, wof);

  k_main<<<B_ * F_ * (K_ / RT), 256, 0, stream>>>(u, v, w1f, b1, w2f, b2,
                                                  wof, bout, cb, xhat, x, dists);
  k_top8<<<B_, 512, 0, stream>>>(dists, topi);
  k_resfin<<<2 * B_, 512, 0, stream>>>(u, v, W1, b1, W2, b2, Wout, bout, cb, xhat,
                                       x, topi, resc2, iwin2, cwhalf);
  k_finw<<<B_, 256, 0, stream>>>(resc2, iwin2, cwhalf, codes, out);
}